// Round 10
// baseline (307.755 us; speedup 1.0000x reference)
//
#include <hip/hip_runtime.h>
#include <hip/hip_bf16.h>

// out[i] = sum_{j!=i} relu(Wd_i@x_j + (Ws_i-Wd_i)@x_i + b_i) * x_j + x_i, 3 steps.
// MFMA 16x16x32 f16 with UNSCALED 2-way f16 split: v = h + m, m = v - (f16)v.
// Edge sum CHAINS through the MFMA C-operand (R12, absmax 1.0 validated):
//   Q = mfma(ah,bh, mfma(ah,bm, mfma(am,bh, mfma(am,bm, bias))))
//   E = mfma(ah,bh, mfma(ah,bm, mfma(am,bh, Q)))
// Ledger: R12 best 60.8us @ (512,4) 16 waves/CU. Occupancy branch DEAD
//   (R10/R13/R14/R16/R17 all spill: true need ~90 regs > 85 budget of 6/SIMD).
// Pipe model (corrected): MfmaUtil==FLOP-throughput-fraction; per-SIMD loads:
//   MFMA ~34%, VALU ~45%, LDS ~54% -> LDS most-loaded; R11/R15/R12 results all
//   consistent with LDS co-binding. All 8 waves read the SAME xsf/xgf -> 8x
//   redundant LDS traffic per CU.
// R18: TWO RECEIVERS PER WAVE (w and w+4), 256-thread blocks (4 waves).
//   Per j: one bh/bm + one xg[2] read feeds BOTH receivers -> LDS reads per
//   receiver HALVE. 32KB LDS -> 4 blocks/CU = 16 waves/CU at (256,4) (128-reg
//   budget). Bonus: 4 independent MFMA chains (2r x 2t), 4-wave barriers.
//   Regs ~100-110 vs 128: the risk. awd resident (32), awsd per-step from L2.
// Spill go/no-go: FETCH<=45MB, WRITE~37MB. FETCH>55 => spilled => R12 fallback.

#define NN 8
#define NSTEPS 3
#define BB 4
#define CC 32
#define HWSZ 9216
#define PX 16
#define NR 2   // receivers per wave

typedef _Float16 f16x8 __attribute__((ext_vector_type(8)));
typedef _Float16 f16x4 __attribute__((ext_vector_type(4)));
typedef _Float16 f16x2 __attribute__((ext_vector_type(2)));
typedef float    f32x4 __attribute__((ext_vector_type(4)));
typedef float    f32x2 __attribute__((ext_vector_type(2)));

#define MFMA(A, B, C) __builtin_amdgcn_mfma_f32_16x16x32_f16((A), (B), (C), 0, 0, 0)

__device__ __forceinline__ void split2(float v, _Float16& h, _Float16& m) {
    h = (_Float16)v;
    m = (_Float16)(v - (float)h);   // unscaled residual
}

// ---- prep: split weights into fragment-major f16x8 tables in workspace ----
// wsf[((r*2+t)*2+s)*512 + lane*8 .. +8]          = awd  frag (Wd split s)
// wsf[16384 + ((r*2+t)*2+s)*512 + lane*8 .. +8]  = awsd frag ((Ws-Wd) split s)
__global__ __launch_bounds__(64, 1)
void prep_w(const float* __restrict__ we, _Float16* __restrict__ wsf) {
    const int r    = blockIdx.x;
    const int lane = threadIdx.x;
    const int col  = lane & 15;
    const int quad = lane >> 4;
    #pragma unroll
    for (int t = 0; t < 2; ++t) {
        const float* wp = we + (size_t)((r * CC + 16 * t + col) * (2 * CC)) + quad * 8;
        f32x4 d0 = *(const f32x4*)wp;
        f32x4 d1 = *(const f32x4*)(wp + 4);
        f32x4 s0 = *(const f32x4*)(wp + CC);
        f32x4 s1 = *(const f32x4*)(wp + CC + 4);
        f16x8 dh, dm, sh, sm;
        #pragma unroll
        for (int k = 0; k < 8; ++k) {
            float d = (k < 4) ? d0[k & 3] : d1[k & 3];
            float s = (k < 4) ? s0[k & 3] : s1[k & 3];
            _Float16 h, m;
            split2(d, h, m);
            dh[k] = h; dm[k] = m;
            split2(s - d, h, m);
            sh[k] = h; sm[k] = m;
        }
        const int base = ((r * 2 + t) * 2) * 512 + lane * 8;
        *(f16x8*)&wsf[base]               = dh;   // s=0
        *(f16x8*)&wsf[base + 512]         = dm;   // s=1
        *(f16x8*)&wsf[16384 + base]       = sh;
        *(f16x8*)&wsf[16384 + base + 512] = sm;
    }
}

__global__ __launch_bounds__(256, 4)
void gcn3_f16w(const float* __restrict__ nodes,
               const _Float16* __restrict__ wsf,
               const float* __restrict__ be,
               float* __restrict__ out) {
    // Fragment-major: slot [lane] holds exactly the 16B that lane consumes.
    // xsf[s][n][lane][e]: B-frag f16 pair; lane = (c>>3)*16 + pixel, e = c&7.
    // xgf[n][t][lane][k]: fp32 gate; lane = ((c>>2)&3)*16 + pixel, k = c&3.
    __shared__ _Float16 xsf[2][NN][64][8];   // 16384 B
    __shared__ float    xgf[NN][2][64][4];   // 16384 B (total 32768)

    const int tid  = threadIdx.x;
    const int w    = tid >> 6;     // wave 0..3 -> receivers w and w+4
    const int lane = tid & 63;
    const int col  = lane & 15;    // pixel; A row m
    const int quad = lane >> 4;    // 0..3

    // ---- resident A-frags: awd for BOTH receivers, from pre-split table ----
    f16x8 awd[NR][2][2];   // [recv][tile t][split] = 32 VGPRs
    #pragma unroll
    for (int r = 0; r < NR; ++r)
        #pragma unroll
        for (int t = 0; t < 2; ++t)
            #pragma unroll
            for (int s = 0; s < 2; ++s)
                awd[r][t][s] = *(const f16x8*)&wsf[(((w + 4 * r) * 2 + t) * 2 + s) * 512 + lane * 8];

    const int q0  = blockIdx.x * PX;
    const int b   = q0 / HWSZ;
    const int hw0 = q0 - b * HWSZ;

    // ---- stage: 1024 f32x2 units over 256 threads (4 iters, NOT unrolled) ----
    #pragma unroll 1
    for (int kk = 0; kk < 4; ++kk) {
        int idx = tid + kk * 256;            // 1024 = 8n * 16c2 * 8p2
        int p2 = (idx & 7) * 2;
        int c2 = ((idx >> 3) & 15) * 2;
        int n  = idx >> 7;
        const float* gp = nodes + (size_t)((n * BB + b) * CC + c2) * HWSZ + hw0 + p2;
        f32x2 v0 = *(const f32x2*)gp;            // channel c2
        f32x2 v1 = *(const f32x2*)(gp + HWSZ);   // channel c2+1
        #pragma unroll
        for (int e = 0; e < 2; ++e) {
            int px = p2 + e;
            _Float16 h0, m0, h1, m1;
            split2(v0[e], h0, m0);
            split2(v1[e], h1, m1);
            *(f16x2*)&xsf[0][n][(c2 >> 3) * 16 + px][c2 & 7] = f16x2{h0, h1};
            *(f16x2*)&xsf[1][n][(c2 >> 3) * 16 + px][c2 & 7] = f16x2{m0, m1};
            *(f32x2*)&xgf[n][c2 >> 4][((c2 >> 2) & 3) * 16 + px][c2 & 3] = f32x2{v0[e], v1[e]};
        }
    }
    __syncthreads();

    f32x4 msg[NR][2];

    #pragma unroll 1
    for (int step = 0; step < NSTEPS; ++step) {
        // ---- Q = (Ws-Wd)_i @ x_i + b, per receiver (awsd+bias from L2) ----
        f32x4 qf[NR][2];
        #pragma unroll
        for (int r = 0; r < NR; ++r) {
            const int iw = w + 4 * r;
            f16x8 bh = *(const f16x8*)&xsf[0][iw][lane][0];
            f16x8 bm = *(const f16x8*)&xsf[1][iw][lane][0];
            #pragma unroll
            for (int t = 0; t < 2; ++t) {
                f16x8 ah = *(const f16x8*)&wsf[16384 + ((iw * 2 + t) * 2 + 0) * 512 + lane * 8];
                f16x8 am = *(const f16x8*)&wsf[16384 + ((iw * 2 + t) * 2 + 1) * 512 + lane * 8];
                f32x4 q  = *(const f32x4*)&be[iw * CC + 16 * t + quad * 4];
                q = MFMA(am, bm, q);     // mm (+bias)
                q = MFMA(am, bh, q);     // mh
                q = MFMA(ah, bm, q);     // hm
                qf[r][t] = MFMA(ah, bh, q); // hh
            }
        }

        #pragma unroll
        for (int r = 0; r < NR; ++r)
            #pragma unroll
            for (int t = 0; t < 2; ++t)
                msg[r][t] = f32x4{0.f, 0.f, 0.f, 0.f};

        // ---- sender loop: ONE bh/bm + xg read serves BOTH receivers ----
        #pragma unroll
        for (int j = 0; j < NN; ++j) {
            f16x8 bh = *(const f16x8*)&xsf[0][j][lane][0];
            f16x8 bm = *(const f16x8*)&xsf[1][j][lane][0];
            f32x4 xg0 = *(const f32x4*)&xgf[j][0][lane][0];
            f32x4 xg1 = *(const f32x4*)&xgf[j][1][lane][0];
            #pragma unroll
            for (int r = 0; r < NR; ++r) {
                if (j == w + 4 * r) {        // wave-uniform: residual
                    #pragma unroll
                    for (int k = 0; k < 4; ++k) {
                        msg[r][0][k] += xg0[k];
                        msg[r][1][k] += xg1[k];
                    }
                } else {
                    #pragma unroll
                    for (int t = 0; t < 2; ++t) {
                        f32x4 e = MFMA(awd[r][t][1], bh, qf[r][t]);   // mh (+Q)
                        e = MFMA(awd[r][t][0], bm, e);                // hm
                        e = MFMA(awd[r][t][0], bh, e);                // hh
                        const f32x4& xg = (t == 0) ? xg0 : xg1;
                        #pragma unroll
                        for (int k = 0; k < 4; ++k) {
                            float g = fmaxf(e[k], 0.f);
                            msg[r][t][k] = fmaf(g, xg[k], msg[r][t][k]);
                        }
                    }
                }
            }
        }

        if (step < NSTEPS - 1) {
            __syncthreads();   // all reads of old x done
            #pragma unroll
            for (int r = 0; r < NR; ++r) {
                const int iw = w + 4 * r;
                #pragma unroll
                for (int t = 0; t < 2; ++t) {
                    f16x4 h4, m4;
                    #pragma unroll
                    for (int k = 0; k < 4; ++k) {
                        _Float16 h, m;
                        split2(msg[r][t][k], h, m);
                        h4[k] = h; m4[k] = m;
                    }
                    // channel c = 16t+quad*4+k -> xsf slot (c>>3)*16+col, elem c&7
                    int lane2 = (2 * t + (quad >> 1)) * 16 + col;
                    int e0    = (quad & 1) * 4;
                    *(f16x4*)&xsf[0][iw][lane2][e0] = h4;
                    *(f16x4*)&xsf[1][iw][lane2][e0] = m4;
                    *(f32x4*)&xgf[iw][t][lane][0] = msg[r][t];   // linear
                }
            }
            __syncthreads();   // new x visible
        }
    }

    // ---- epilogue: direct fragment stores (per (r,t,k): 16-lane 64B segs) ----
    #pragma unroll
    for (int r = 0; r < NR; ++r)
        #pragma unroll
        for (int t = 0; t < 2; ++t)
            #pragma unroll
            for (int k = 0; k < 4; ++k)
                out[(size_t)(((w + 4 * r) * BB + b) * CC + 16 * t + quad * 4 + k) * HWSZ + hw0 + col] = msg[r][t][k];
}

extern "C" void kernel_launch(void* const* d_in, const int* in_sizes, int n_in,
                              void* d_out, int out_size, void* d_ws, size_t ws_size,
                              hipStream_t stream) {
    const float* nodes  = (const float*)d_in[0];
    const float* W_edge = (const float*)d_in[1];
    const float* b_edge = (const float*)d_in[2];
    float* outp = (float*)d_out;
    _Float16* wsf = (_Float16*)d_ws;   // 64 KB used: [0,32K) awd frags, [32K,64K) awsd frags

    prep_w<<<dim3(NN), dim3(64), 0, stream>>>(W_edge, wsf);

    dim3 grid((BB * HWSZ) / PX);   // 2304 blocks of 256
    dim3 block(256);
    gcn3_f16w<<<grid, block, 0, stream>>>(nodes, wsf, b_edge, outp);
}

// Round 11
// 144.425 us; speedup vs baseline: 2.1309x; 2.1309x over previous
//
#include <hip/hip_runtime.h>
#include <hip/hip_bf16.h>

// out[i] = sum_{j!=i} relu(Wd_i@x_j + (Ws_i-Wd_i)@x_i + b_i) * x_j + x_i, 3 steps.
// MFMA 16x16x32 f16, UNSCALED 2-way split v=h+m, C-operand-chained (R12 math,
// absmax 1.0 validated).
// Ledger: R12 best 60.8us @ (512,4). Occupancy branch DEAD (R10/13/14/16/17
//   spill; 512-thr granularity = 4 waves/SIMD-or-spill). LDS pipe ~57-60% =
//   most-loaded resource; R15 (2x ILP flat) says throughput- not latency-bound.
// R18 FAILED: 2-recv/wave with UNROLLED j-loop -> scheduler hoisting blew the
//   arch-side reg peak (64-arch split, FETCH 270MB) despite ~116-reg census.
// R19 (last structural try, then R12 fallback): same 2-recv dataflow,
//   REGISTER-DISCIPLINED schedule:
//   - j-loop ROLLED (unroll 1): per-j state transient (~52 arch live);
//     R15 proved cross-sender ILP is worthless -> rolling is perf-neutral.
//   - persistent awd/qf/msg are MFMA operands -> acc-file eligible.
//   - staging rolled (R17). One bh/bm+xg LDS read serves BOTH receivers:
//     per-tile LDS reads 256 -> 144 b128 (-44%).
//   (256,4): 128-reg budget, 4 blocks/CU x 32KB = 128KB LDS.
// Spill go/no-go: FETCH<=45MB, WRITE~37MB. FETCH>55 => revert to R12.

#define NN 8
#define NSTEPS 3
#define BB 4
#define CC 32
#define HWSZ 9216
#define PX 16
#define NR 2   // receivers per wave

typedef _Float16 f16x8 __attribute__((ext_vector_type(8)));
typedef _Float16 f16x4 __attribute__((ext_vector_type(4)));
typedef _Float16 f16x2 __attribute__((ext_vector_type(2)));
typedef float    f32x4 __attribute__((ext_vector_type(4)));
typedef float    f32x2 __attribute__((ext_vector_type(2)));

#define MFMA(A, B, C) __builtin_amdgcn_mfma_f32_16x16x32_f16((A), (B), (C), 0, 0, 0)

__device__ __forceinline__ void split2(float v, _Float16& h, _Float16& m) {
    h = (_Float16)v;
    m = (_Float16)(v - (float)h);   // unscaled residual
}

// ---- prep: split weights into fragment-major f16x8 tables in workspace ----
// wsf[((r*2+t)*2+s)*512 + lane*8 .. +8]          = awd  frag (Wd split s)
// wsf[16384 + ((r*2+t)*2+s)*512 + lane*8 .. +8]  = awsd frag ((Ws-Wd) split s)
__global__ __launch_bounds__(64, 1)
void prep_w(const float* __restrict__ we, _Float16* __restrict__ wsf) {
    const int r    = blockIdx.x;
    const int lane = threadIdx.x;
    const int col  = lane & 15;
    const int quad = lane >> 4;
    #pragma unroll
    for (int t = 0; t < 2; ++t) {
        const float* wp = we + (size_t)((r * CC + 16 * t + col) * (2 * CC)) + quad * 8;
        f32x4 d0 = *(const f32x4*)wp;
        f32x4 d1 = *(const f32x4*)(wp + 4);
        f32x4 s0 = *(const f32x4*)(wp + CC);
        f32x4 s1 = *(const f32x4*)(wp + CC + 4);
        f16x8 dh, dm, sh, sm;
        #pragma unroll
        for (int k = 0; k < 8; ++k) {
            float d = (k < 4) ? d0[k & 3] : d1[k & 3];
            float s = (k < 4) ? s0[k & 3] : s1[k & 3];
            _Float16 h, m;
            split2(d, h, m);
            dh[k] = h; dm[k] = m;
            split2(s - d, h, m);
            sh[k] = h; sm[k] = m;
        }
        const int base = ((r * 2 + t) * 2) * 512 + lane * 8;
        *(f16x8*)&wsf[base]               = dh;   // s=0
        *(f16x8*)&wsf[base + 512]         = dm;   // s=1
        *(f16x8*)&wsf[16384 + base]       = sh;
        *(f16x8*)&wsf[16384 + base + 512] = sm;
    }
}

__global__ __launch_bounds__(256, 4)
void gcn3_f16w(const float* __restrict__ nodes,
               const _Float16* __restrict__ wsf,
               const float* __restrict__ be,
               float* __restrict__ out) {
    // Fragment-major: slot [lane] holds exactly the 16B that lane consumes.
    // xsf[s][n][lane][e]: B-frag f16 pair; lane = (c>>3)*16 + pixel, e = c&7.
    // xgf[n][t][lane][k]: fp32 gate; lane = ((c>>2)&3)*16 + pixel, k = c&3.
    __shared__ _Float16 xsf[2][NN][64][8];   // 16384 B
    __shared__ float    xgf[NN][2][64][4];   // 16384 B (total 32768)

    const int tid  = threadIdx.x;
    const int w    = tid >> 6;     // wave 0..3 -> receivers w and w+4
    const int lane = tid & 63;
    const int col  = lane & 15;    // pixel; A row m
    const int quad = lane >> 4;    // 0..3

    // ---- resident A-frags: awd for BOTH receivers (acc-file eligible) ----
    f16x8 awd[NR][2][2];   // [recv][tile t][split]
    #pragma unroll
    for (int r = 0; r < NR; ++r)
        #pragma unroll
        for (int t = 0; t < 2; ++t)
            #pragma unroll
            for (int s = 0; s < 2; ++s)
                awd[r][t][s] = *(const f16x8*)&wsf[(((w + 4 * r) * 2 + t) * 2 + s) * 512 + lane * 8];

    const int q0  = blockIdx.x * PX;
    const int b   = q0 / HWSZ;
    const int hw0 = q0 - b * HWSZ;

    // ---- stage: 1024 f32x2 units over 256 threads (4 iters, rolled) ----
    #pragma unroll 1
    for (int kk = 0; kk < 4; ++kk) {
        int idx = tid + kk * 256;            // 1024 = 8n * 16c2 * 8p2
        int p2 = (idx & 7) * 2;
        int c2 = ((idx >> 3) & 15) * 2;
        int n  = idx >> 7;
        const float* gp = nodes + (size_t)((n * BB + b) * CC + c2) * HWSZ + hw0 + p2;
        f32x2 v0 = *(const f32x2*)gp;            // channel c2
        f32x2 v1 = *(const f32x2*)(gp + HWSZ);   // channel c2+1
        #pragma unroll
        for (int e = 0; e < 2; ++e) {
            int px = p2 + e;
            _Float16 h0, m0, h1, m1;
            split2(v0[e], h0, m0);
            split2(v1[e], h1, m1);
            *(f16x2*)&xsf[0][n][(c2 >> 3) * 16 + px][c2 & 7] = f16x2{h0, h1};
            *(f16x2*)&xsf[1][n][(c2 >> 3) * 16 + px][c2 & 7] = f16x2{m0, m1};
            *(f32x2*)&xgf[n][c2 >> 4][((c2 >> 2) & 3) * 16 + px][c2 & 3] = f32x2{v0[e], v1[e]};
        }
    }
    __syncthreads();

    f32x4 msg[NR][2];

    #pragma unroll 1
    for (int step = 0; step < NSTEPS; ++step) {
        // ---- Q = (Ws-Wd)_i @ x_i + b, per receiver (awsd+bias from L2) ----
        f32x4 qf[NR][2];
        #pragma unroll
        for (int r = 0; r < NR; ++r) {
            const int iw = w + 4 * r;
            f16x8 bh = *(const f16x8*)&xsf[0][iw][lane][0];
            f16x8 bm = *(const f16x8*)&xsf[1][iw][lane][0];
            #pragma unroll
            for (int t = 0; t < 2; ++t) {
                f16x8 ah = *(const f16x8*)&wsf[16384 + ((iw * 2 + t) * 2 + 0) * 512 + lane * 8];
                f16x8 am = *(const f16x8*)&wsf[16384 + ((iw * 2 + t) * 2 + 1) * 512 + lane * 8];
                f32x4 q  = *(const f32x4*)&be[iw * CC + 16 * t + quad * 4];
                q = MFMA(am, bm, q);        // mm (+bias)
                q = MFMA(am, bh, q);        // mh
                q = MFMA(ah, bm, q);        // hm
                qf[r][t] = MFMA(ah, bh, q); // hh
            }
            msg[r][0] = f32x4{0.f, 0.f, 0.f, 0.f};
            msg[r][1] = f32x4{0.f, 0.f, 0.f, 0.f};
        }

        // ---- sender loop, ROLLED: one bh/bm + xg read serves BOTH receivers ----
        #pragma unroll 1
        for (int j = 0; j < NN; ++j) {
            f16x8 bh = *(const f16x8*)&xsf[0][j][lane][0];
            f16x8 bm = *(const f16x8*)&xsf[1][j][lane][0];
            f32x4 xg0 = *(const f32x4*)&xgf[j][0][lane][0];
            f32x4 xg1 = *(const f32x4*)&xgf[j][1][lane][0];
            #pragma unroll
            for (int r = 0; r < NR; ++r) {
                if (j == w + 4 * r) {        // wave-uniform: residual
                    #pragma unroll
                    for (int k = 0; k < 4; ++k) {
                        msg[r][0][k] += xg0[k];
                        msg[r][1][k] += xg1[k];
                    }
                } else {
                    #pragma unroll
                    for (int t = 0; t < 2; ++t) {
                        f32x4 e = MFMA(awd[r][t][1], bh, qf[r][t]);   // mh (+Q)
                        e = MFMA(awd[r][t][0], bm, e);                // hm
                        e = MFMA(awd[r][t][0], bh, e);                // hh
                        const f32x4& xg = (t == 0) ? xg0 : xg1;
                        #pragma unroll
                        for (int k = 0; k < 4; ++k) {
                            float g = fmaxf(e[k], 0.f);
                            msg[r][t][k] = fmaf(g, xg[k], msg[r][t][k]);
                        }
                    }
                }
            }
        }

        if (step < NSTEPS - 1) {
            __syncthreads();   // all reads of old x done
            #pragma unroll
            for (int r = 0; r < NR; ++r) {
                const int iw = w + 4 * r;
                #pragma unroll
                for (int t = 0; t < 2; ++t) {
                    f16x4 h4, m4;
                    #pragma unroll
                    for (int k = 0; k < 4; ++k) {
                        _Float16 h, m;
                        split2(msg[r][t][k], h, m);
                        h4[k] = h; m4[k] = m;
                    }
                    // channel c = 16t+quad*4+k -> xsf slot (c>>3)*16+col, elem c&7
                    int lane2 = (2 * t + (quad >> 1)) * 16 + col;
                    int e0    = (quad & 1) * 4;
                    *(f16x4*)&xsf[0][iw][lane2][e0] = h4;
                    *(f16x4*)&xsf[1][iw][lane2][e0] = m4;
                    *(f32x4*)&xgf[iw][t][lane][0] = msg[r][t];   // linear
                }
            }
            __syncthreads();   // new x visible
        }
    }

    // ---- epilogue: direct fragment stores (per (r,t,k): 16-lane 64B segs) ----
    #pragma unroll
    for (int r = 0; r < NR; ++r)
        #pragma unroll
        for (int t = 0; t < 2; ++t)
            #pragma unroll
            for (int k = 0; k < 4; ++k)
                out[(size_t)(((w + 4 * r) * BB + b) * CC + 16 * t + quad * 4 + k) * HWSZ + hw0 + col] = msg[r][t][k];
}

extern "C" void kernel_launch(void* const* d_in, const int* in_sizes, int n_in,
                              void* d_out, int out_size, void* d_ws, size_t ws_size,
                              hipStream_t stream) {
    const float* nodes  = (const float*)d_in[0];
    const float* W_edge = (const float*)d_in[1];
    const float* b_edge = (const float*)d_in[2];
    float* outp = (float*)d_out;
    _Float16* wsf = (_Float16*)d_ws;   // 64 KB used: [0,32K) awd frags, [32K,64K) awsd frags

    prep_w<<<dim3(NN), dim3(64), 0, stream>>>(W_edge, wsf);

    dim3 grid((BB * HWSZ) / PX);   // 2304 blocks of 256
    dim3 block(256);
    gcn3_f16w<<<grid, block, 0, stream>>>(nodes, wsf, b_edge, outp);
}